// Round 1
// baseline (2011.106 us; speedup 1.0000x reference)
//
#include <hip/hip_runtime.h>

// LSTMPredictor: 2-layer LSTMCell (H=51) over L=1000 steps + 100 autoregressive
// future steps, B=256 independent chains, scalar output per step.
// One block per batch element (256 blocks = 1 block/CU on MI355X).
// Thread j<204 owns gate row j of both layers, weights in registers.

#define B_  256
#define L_  1000
#define H_  51
#define F_  100
#define G4  (4 * H_)      // 204
#define T_  (L_ + F_)     // 1100

__device__ __forceinline__ float sigf(float v) {
    return 1.0f / (1.0f + expf(-v));
}

__global__ __launch_bounds__(256, 1)
void lstm_pred_kernel(const float* __restrict__ x,
                      const float* __restrict__ W_ih1, const float* __restrict__ W_hh1,
                      const float* __restrict__ b_ih1, const float* __restrict__ b_hh1,
                      const float* __restrict__ W_ih2, const float* __restrict__ W_hh2,
                      const float* __restrict__ b_ih2, const float* __restrict__ b_hh2,
                      const float* __restrict__ W_lin, const float* __restrict__ b_lin,
                      float* __restrict__ out)
{
    __shared__ float xrow[L_];
    __shared__ float gates[G4];
    __shared__ float h1s[H_];
    __shared__ float h2s[H_];
    __shared__ float out_s;

    const int j = threadIdx.x;
    const int b = blockIdx.x;

    // Stage this batch element's input row in LDS (coalesced, one-time).
    for (int i = j; i < L_; i += 256) xrow[i] = x[b * L_ + i];
    if (j < H_) { h1s[j] = 0.0f; h2s[j] = 0.0f; }

    // Per-thread weight registers: row j of W_hh1, W_ih2, W_hh2 (+ scalars).
    float whh1[H_], wih2[H_], whh2[H_];
    float wih1 = 0.0f, bias1 = 0.0f, bias2 = 0.0f, wlin = 0.0f;
    if (j < G4) {
        wih1  = W_ih1[j];
        bias1 = b_ih1[j] + b_hh1[j];
        bias2 = b_ih2[j] + b_hh2[j];
#pragma unroll
        for (int k = 0; k < H_; ++k) {
            whh1[k] = W_hh1[j * H_ + k];
            wih2[k] = W_ih2[j * H_ + k];
            whh2[k] = W_hh2[j * H_ + k];
        }
    }
    if (j < H_) wlin = W_lin[j];
    const float blin = b_lin[0];

    float c1 = 0.0f, c2 = 0.0f;
    __syncthreads();

    float* outp = out + (size_t)b * T_;

    for (int t = 0; t < T_; ++t) {
        const float xv = (t < L_) ? xrow[t] : out_s;

        // ---- layer-1 gates: 204 independent 51-dots, 4 partial accumulators
        if (j < G4) {
            float a0 = fmaf(wih1, xv, bias1), a1 = 0.f, a2 = 0.f, a3 = 0.f;
#pragma unroll
            for (int k = 0; k + 3 < H_; k += 4) {
                a0 = fmaf(whh1[k + 0], h1s[k + 0], a0);
                a1 = fmaf(whh1[k + 1], h1s[k + 1], a1);
                a2 = fmaf(whh1[k + 2], h1s[k + 2], a2);
                a3 = fmaf(whh1[k + 3], h1s[k + 3], a3);
            }
            // H_ = 51: tail k = 48..50 handled above for 48,49,50? 48+3<51 false.
#pragma unroll
            for (int k = (H_ / 4) * 4; k < H_; ++k)
                a0 = fmaf(whh1[k], h1s[k], a0);
            gates[j] = (a0 + a1) + (a2 + a3);
        }
        __syncthreads();

        // ---- layer-1 state update (threads 0..50)
        if (j < H_) {
            float ig = sigf(gates[j]);
            float fg = sigf(gates[j + H_]);
            float gg = tanhf(gates[j + 2 * H_]);
            float og = sigf(gates[j + 3 * H_]);
            c1 = fmaf(fg, c1, ig * gg);
            h1s[j] = og * tanhf(c1);
        }
        __syncthreads();

        // ---- layer-2 gates: two 51-dots per row, 4 partial accumulators
        if (j < G4) {
            float a0 = bias2, a1 = 0.f, a2 = 0.f, a3 = 0.f;
#pragma unroll
            for (int k = 0; k + 1 < H_; k += 2) {
                a0 = fmaf(wih2[k + 0], h1s[k + 0], a0);
                a1 = fmaf(whh2[k + 0], h2s[k + 0], a1);
                a2 = fmaf(wih2[k + 1], h1s[k + 1], a2);
                a3 = fmaf(whh2[k + 1], h2s[k + 1], a3);
            }
#pragma unroll
            for (int k = (H_ / 2) * 2; k < H_; ++k) {
                a0 = fmaf(wih2[k], h1s[k], a0);
                a1 = fmaf(whh2[k], h2s[k], a1);
            }
            gates[j] = (a0 + a2) + (a1 + a3);
        }
        __syncthreads();

        // ---- layer-2 state update + output projection
        float p = 0.0f;
        if (j < H_) {
            float ig = sigf(gates[j]);
            float fg = sigf(gates[j + H_]);
            float gg = tanhf(gates[j + 2 * H_]);
            float og = sigf(gates[j + 3 * H_]);
            c2 = fmaf(fg, c2, ig * gg);
            float h2n = og * tanhf(c2);
            h2s[j] = h2n;
            p = h2n * wlin;
        }
        if (j < 64) {  // wave 0: reduce 51 partials (lanes 51..63 contribute 0)
#pragma unroll
            for (int off = 32; off > 0; off >>= 1) p += __shfl_down(p, off);
            if (j == 0) {
                float o = p + blin;
                out_s = o;
                outp[t] = o;
            }
        }
        __syncthreads();
    }
}

extern "C" void kernel_launch(void* const* d_in, const int* in_sizes, int n_in,
                              void* d_out, int out_size, void* d_ws, size_t ws_size,
                              hipStream_t stream)
{
    const float* x     = (const float*)d_in[0];
    const float* W_ih1 = (const float*)d_in[1];
    const float* W_hh1 = (const float*)d_in[2];
    const float* b_ih1 = (const float*)d_in[3];
    const float* b_hh1 = (const float*)d_in[4];
    const float* W_ih2 = (const float*)d_in[5];
    const float* W_hh2 = (const float*)d_in[6];
    const float* b_ih2 = (const float*)d_in[7];
    const float* b_hh2 = (const float*)d_in[8];
    const float* W_lin = (const float*)d_in[9];
    const float* b_lin = (const float*)d_in[10];
    float* out = (float*)d_out;

    lstm_pred_kernel<<<B_, 256, 0, stream>>>(x, W_ih1, W_hh1, b_ih1, b_hh1,
                                             W_ih2, W_hh2, b_ih2, b_hh2,
                                             W_lin, b_lin, out);
}

// Round 2
// 1645.232 us; speedup vs baseline: 1.2224x; 1.2224x over previous
//
#include <hip/hip_runtime.h>

// LSTMPredictor: 2-layer LSTMCell (H=51), L=1000 seq steps + 100 autoregressive
// future steps, B=256 independent chains.
// One block per batch element; 512 threads:
//   threads 0..203   : layer-1 gate rows (weights in regs, 52 floats)
//   threads 256..459 : layer-2 gate rows (weights in regs, 104 floats)
// Software pipeline: while L2 computes gates2(t), L1 computes the h-part of
// gates1(t+1); the x*W_ih1 rank-1 term is added at update time so the
// autoregressive feedback (x(t+1)=out(t)) only serializes the cheap update.

#define B_  256
#define L_  1000
#define H_  51
#define HP  52      // H padded to multiple of 4 for ds_read_b128
#define G4  204     // 4*H
#define T_  1100
#define NQ  13      // HP/4

__device__ __forceinline__ float sigf(float v) {
    return 1.0f / (1.0f + expf(-v));
}

__global__ __launch_bounds__(512, 2)
void lstm_pred_kernel(const float* __restrict__ x,
                      const float* __restrict__ W_ih1, const float* __restrict__ W_hh1,
                      const float* __restrict__ b_ih1, const float* __restrict__ b_hh1,
                      const float* __restrict__ W_ih2, const float* __restrict__ W_hh2,
                      const float* __restrict__ b_ih2, const float* __restrict__ b_hh2,
                      const float* __restrict__ W_lin, const float* __restrict__ b_lin,
                      float* __restrict__ out)
{
    __shared__ float xrow[L_];
    __shared__ alignas(16) float gates1[G4];
    __shared__ alignas(16) float gates2[G4];
    __shared__ alignas(16) float h1s[HP];
    __shared__ alignas(16) float h2s[HP];
    __shared__ float out_s;

    const int tid = threadIdx.x;
    const int b   = blockIdx.x;

    // Stage input row (one-time).
    for (int i = tid; i < L_; i += 512) xrow[i] = x[(size_t)b * L_ + i];
    if (tid < HP) { h1s[tid] = 0.0f; h2s[tid] = 0.0f; }

    const bool isL1 = (tid < G4);
    const bool isL2 = (tid >= 256) && (tid < 256 + G4);
    const int  j2   = tid - 256;

    // ---- per-thread weights in registers (static-index only -> SROA) ----
    float4 whh1[NQ];
    float  bias1 = 0.f;
    if (isL1) {
        bias1 = b_ih1[tid] + b_hh1[tid];
        const float* r = W_hh1 + tid * H_;
#pragma unroll
        for (int q = 0; q < NQ; ++q) {
            whh1[q].x = (4*q+0 < H_) ? r[4*q+0] : 0.f;
            whh1[q].y = (4*q+1 < H_) ? r[4*q+1] : 0.f;
            whh1[q].z = (4*q+2 < H_) ? r[4*q+2] : 0.f;
            whh1[q].w = (4*q+3 < H_) ? r[4*q+3] : 0.f;
        }
    }
    float4 wih2[NQ], whh2[NQ];
    float  bias2 = 0.f;
    if (isL2) {
        bias2 = b_ih2[j2] + b_hh2[j2];
        const float* ri = W_ih2 + j2 * H_;
        const float* rh = W_hh2 + j2 * H_;
#pragma unroll
        for (int q = 0; q < NQ; ++q) {
            wih2[q].x = (4*q+0 < H_) ? ri[4*q+0] : 0.f;
            wih2[q].y = (4*q+1 < H_) ? ri[4*q+1] : 0.f;
            wih2[q].z = (4*q+2 < H_) ? ri[4*q+2] : 0.f;
            wih2[q].w = (4*q+3 < H_) ? ri[4*q+3] : 0.f;
            whh2[q].x = (4*q+0 < H_) ? rh[4*q+0] : 0.f;
            whh2[q].y = (4*q+1 < H_) ? rh[4*q+1] : 0.f;
            whh2[q].z = (4*q+2 < H_) ? rh[4*q+2] : 0.f;
            whh2[q].w = (4*q+3 < H_) ? rh[4*q+3] : 0.f;
        }
    }
    // update-lane extras
    float wi_i = 0.f, wi_f = 0.f, wi_g = 0.f, wi_o = 0.f, wlin = 0.f;
    if (tid < H_) {
        wi_i = W_ih1[tid];
        wi_f = W_ih1[tid + H_];
        wi_g = W_ih1[tid + 2 * H_];
        wi_o = W_ih1[tid + 3 * H_];
    }
    if (tid >= 256 && j2 < H_) wlin = W_lin[j2];
    const float blin = b_lin[0];

    float c1 = 0.f, c2 = 0.f;
    float* outp = out + (size_t)b * T_;

    // ---- prologue: h1(0) (h1(-1)=0 so gates1 partial = bias1) ----
    if (isL1) gates1[tid] = bias1;
    __syncthreads();
    if (tid < H_) {
        const float xv = xrow[0];
        float gi = fmaf(wi_i, xv, gates1[tid]);
        float gf = fmaf(wi_f, xv, gates1[tid + H_]);
        float gg = fmaf(wi_g, xv, gates1[tid + 2 * H_]);
        float go = fmaf(wi_o, xv, gates1[tid + 3 * H_]);
        float ig = sigf(gi), fg = sigf(gf), g = tanhf(gg), og = sigf(go);
        c1 = fmaf(fg, c1, ig * g);
        h1s[tid] = og * tanhf(c1);
    }
    __syncthreads();

    // ---- main loop: iteration t computes h2(t)/out(t) and h1(t+1) ----
    for (int t = 0; t < T_; ++t) {
        // Phase A: dots (h1s = h1(t), h2s = h2(t-1))
        if (isL1) {          // partial gates1(t+1): bias1 + W_hh1 @ h1(t)
            float a0 = bias1, a1 = 0.f, a2 = 0.f, a3 = 0.f;
            const float4* h4 = (const float4*)h1s;
#pragma unroll
            for (int q = 0; q < NQ; ++q) {
                float4 hv = h4[q];
                a0 = fmaf(whh1[q].x, hv.x, a0);
                a1 = fmaf(whh1[q].y, hv.y, a1);
                a2 = fmaf(whh1[q].z, hv.z, a2);
                a3 = fmaf(whh1[q].w, hv.w, a3);
            }
            gates1[tid] = (a0 + a1) + (a2 + a3);
        }
        if (isL2) {          // gates2(t) = bias2 + W_ih2 @ h1(t) + W_hh2 @ h2(t-1)
            float a0 = bias2, a1 = 0.f, a2 = 0.f, a3 = 0.f;
            float b0 = 0.f,   b1 = 0.f, b2 = 0.f, b3 = 0.f;
            const float4* g4v = (const float4*)h1s;
            const float4* k4v = (const float4*)h2s;
#pragma unroll
            for (int q = 0; q < NQ; ++q) {
                float4 hv = g4v[q];
                float4 kv = k4v[q];
                a0 = fmaf(wih2[q].x, hv.x, a0);
                a1 = fmaf(wih2[q].y, hv.y, a1);
                a2 = fmaf(wih2[q].z, hv.z, a2);
                a3 = fmaf(wih2[q].w, hv.w, a3);
                b0 = fmaf(whh2[q].x, kv.x, b0);
                b1 = fmaf(whh2[q].y, kv.y, b1);
                b2 = fmaf(whh2[q].z, kv.z, b2);
                b3 = fmaf(whh2[q].w, kv.w, b3);
            }
            gates2[j2] = ((a0 + a1) + (a2 + a3)) + ((b0 + b1) + (b2 + b3));
        }
        __syncthreads();

        // Phase B1: layer-2 update + output (wave 4: threads 256..319)
        if (tid >= 256 && tid < 320) {
            float p = 0.f;
            if (j2 < H_) {
                float gi = gates2[j2];
                float gf = gates2[j2 + H_];
                float gg = gates2[j2 + 2 * H_];
                float go = gates2[j2 + 3 * H_];
                float ig = sigf(gi), fg = sigf(gf), g = tanhf(gg), og = sigf(go);
                c2 = fmaf(fg, c2, ig * g);
                float h2n = og * tanhf(c2);
                h2s[j2] = h2n;
                p = h2n * wlin;
            }
#pragma unroll
            for (int off = 32; off > 0; off >>= 1) p += __shfl_down(p, off);
            if (j2 == 0) {
                float o = p + blin;
                out_s = o;
                outp[t] = o;
            }
        }
        __syncthreads();

        // Phase B2: layer-1 update -> h1(t+1)  (wave 0: threads 0..63)
        if (tid < H_) {
            const float xv = (t + 1 < L_) ? xrow[t + 1] : out_s;
            float gi = fmaf(wi_i, xv, gates1[tid]);
            float gf = fmaf(wi_f, xv, gates1[tid + H_]);
            float gg = fmaf(wi_g, xv, gates1[tid + 2 * H_]);
            float go = fmaf(wi_o, xv, gates1[tid + 3 * H_]);
            float ig = sigf(gi), fg = sigf(gf), g = tanhf(gg), og = sigf(go);
            c1 = fmaf(fg, c1, ig * g);
            h1s[tid] = og * tanhf(c1);
        }
        __syncthreads();
    }
}

extern "C" void kernel_launch(void* const* d_in, const int* in_sizes, int n_in,
                              void* d_out, int out_size, void* d_ws, size_t ws_size,
                              hipStream_t stream)
{
    const float* x     = (const float*)d_in[0];
    const float* W_ih1 = (const float*)d_in[1];
    const float* W_hh1 = (const float*)d_in[2];
    const float* b_ih1 = (const float*)d_in[3];
    const float* b_hh1 = (const float*)d_in[4];
    const float* W_ih2 = (const float*)d_in[5];
    const float* W_hh2 = (const float*)d_in[6];
    const float* b_ih2 = (const float*)d_in[7];
    const float* b_hh2 = (const float*)d_in[8];
    const float* W_lin = (const float*)d_in[9];
    const float* b_lin = (const float*)d_in[10];
    float* out = (float*)d_out;

    lstm_pred_kernel<<<B_, 512, 0, stream>>>(x, W_ih1, W_hh1, b_ih1, b_hh1,
                                             W_ih2, W_hh2, b_ih2, b_hh2,
                                             W_lin, b_lin, out);
}

// Round 3
// 1008.214 us; speedup vs baseline: 1.9947x; 1.6318x over previous
//
#include <hip/hip_runtime.h>

// LSTMPredictor: 2-layer LSTMCell (H=51), L=1000 steps + 100 autoregressive,
// B=256 chains. One block per batch element, 768 threads in 3 groups of 204:
//   G0 (tid   0..203): row j of W_hh1  -> gates1 partial for step t+1
//   G1 (tid 256..459): row j of W_ih2  -> gatesA(t)
//   G2 (tid 512..715): row j of W_hh2  -> gatesB(t)
// Every thread holds exactly ONE 52-float weight row in registers (uniform
// code path => single array => no cross-group liveness blowup / spill).
// Hot loop: 2 barriers/step, L1-update (wave 0) and L2-update+out (wave 4)
// run concurrently. Future loop (x <- out feedback): 3 barriers/step.

#define B_   256
#define L_   1000
#define H_   51
#define HP   52      // padded (element 51 stays 0)
#define G4   204
#define GP   208     // padded group stride in gall
#define T_   1100
#define NQ   13      // HP/4 float4 per row

__device__ __forceinline__ float frcp(float v) { return __builtin_amdgcn_rcpf(v); }
__device__ __forceinline__ float sigf(float v) {
    return frcp(1.0f + __expf(-v));      // exp->0 or inf are both safe
}
__device__ __forceinline__ float tanh_fast(float v) {
    float a = fminf(fmaxf(v, -9.0f), 9.0f);
    float e = __expf(2.0f * a);
    return (e - 1.0f) * frcp(e + 1.0f);
}

__global__ __launch_bounds__(768, 3)
void lstm_pred_kernel(const float* __restrict__ x,
                      const float* __restrict__ W_ih1, const float* __restrict__ W_hh1,
                      const float* __restrict__ b_ih1, const float* __restrict__ b_hh1,
                      const float* __restrict__ W_ih2, const float* __restrict__ W_hh2,
                      const float* __restrict__ b_ih2, const float* __restrict__ b_hh2,
                      const float* __restrict__ W_lin, const float* __restrict__ b_lin,
                      float* __restrict__ out)
{
    __shared__ float xrow[L_];
    __shared__ alignas(16) float gall[3 * GP];  // [0:204)=gates1p, [GP..)=gatesA, [2GP..)=gatesB
    __shared__ alignas(16) float hs[2][HP];     // hs[0]=h1, hs[1]=h2
    __shared__ float out_s;

    const int tid = threadIdx.x;
    const int b   = blockIdx.x;
    const int g   = tid >> 8;          // group 0,1,2
    const int j   = tid & 255;         // row within group
    const bool act = (j < G4);
    const int s   = (g == 2) ? 1 : 0;  // h-source: h2 for G2, else h1

    for (int i = tid; i < L_; i += 768) xrow[i] = x[(size_t)b * L_ + i];
    if (tid < HP) { hs[0][tid] = 0.0f; hs[1][tid] = 0.0f; }

    // ---- one weight row per thread, in registers ----
    const float* wrow = (g == 0) ? (W_hh1 + j * H_)
                      : (g == 1) ? (W_ih2 + j * H_)
                                 : (W_hh2 + j * H_);
    float bias = 0.0f;
    float4 wA[NQ];
    if (act) {
        if (g == 0)      bias = b_ih1[j] + b_hh1[j];
        else if (g == 1) bias = b_ih2[j] + b_hh2[j];
#pragma unroll
        for (int q = 0; q < NQ; ++q) {
            wA[q].x = (4*q+0 < H_) ? wrow[4*q+0] : 0.0f;
            wA[q].y = (4*q+1 < H_) ? wrow[4*q+1] : 0.0f;
            wA[q].z = (4*q+2 < H_) ? wrow[4*q+2] : 0.0f;
            wA[q].w = (4*q+3 < H_) ? wrow[4*q+3] : 0.0f;
        }
    } else {
#pragma unroll
        for (int q = 0; q < NQ; ++q) wA[q] = make_float4(0.f, 0.f, 0.f, 0.f);
    }
    float* gdst = gall + g * GP + j;

    // update-lane extras
    float wi0 = 0.f, wi1 = 0.f, wi2 = 0.f, wi3 = 0.f, wlin = 0.f;
    if (tid < H_) {
        wi0 = W_ih1[tid];
        wi1 = W_ih1[tid + H_];
        wi2 = W_ih1[tid + 2 * H_];
        wi3 = W_ih1[tid + 3 * H_];
    }
    if (tid >= 256 && tid < 256 + H_) wlin = W_lin[tid - 256];
    const float blin = b_lin[0];

    float c1 = 0.f, c2 = 0.f;
    float* outp = out + (size_t)b * T_;

    // ---- prologue: h1(0)  (h1(-1)=0 -> gates1 partial = bias1) ----
    if (g == 0 && act) gall[j] = bias;
    __syncthreads();
    if (tid < H_) {
        const float xv = xrow[0];
        float gi = fmaf(wi0, xv, gall[tid]);
        float gf = fmaf(wi1, xv, gall[tid + H_]);
        float gg = fmaf(wi2, xv, gall[tid + 2 * H_]);
        float go = fmaf(wi3, xv, gall[tid + 3 * H_]);
        float ig = sigf(gi), fg = sigf(gf), gv = tanh_fast(gg), og = sigf(go);
        c1 = fmaf(fg, c1, ig * gv);
        hs[0][tid] = og * tanh_fast(c1);
    }
    __syncthreads();

    // ================= hot loop: t = 0 .. L_-2 (x from xrow) =================
    for (int t = 0; t < L_ - 1; ++t) {
        // Phase A: all three matvecs in parallel
        if (act) {
            const float4* h4 = (const float4*)hs[s];
            float a0 = bias, a1 = 0.f, a2 = 0.f, a3 = 0.f;
#pragma unroll
            for (int q = 0; q < NQ; ++q) {
                float4 hv = h4[q];
                a0 = fmaf(wA[q].x, hv.x, a0);
                a1 = fmaf(wA[q].y, hv.y, a1);
                a2 = fmaf(wA[q].z, hv.z, a2);
                a3 = fmaf(wA[q].w, hv.w, a3);
            }
            gdst[0] = (a0 + a1) + (a2 + a3);
        }
        __syncthreads();

        // Phase B1 (wave 4): layer-2 update + output
        if (tid >= 256 && tid < 320) {
            float p = 0.f;
            const int q2 = tid - 256;
            if (q2 < H_) {
                float gi = gall[GP + q2]          + gall[2*GP + q2];
                float gf = gall[GP + q2 +   H_]   + gall[2*GP + q2 +   H_];
                float gg = gall[GP + q2 + 2*H_]   + gall[2*GP + q2 + 2*H_];
                float go = gall[GP + q2 + 3*H_]   + gall[2*GP + q2 + 3*H_];
                float ig = sigf(gi), fg = sigf(gf), gv = tanh_fast(gg), og = sigf(go);
                c2 = fmaf(fg, c2, ig * gv);
                float h2n = og * tanh_fast(c2);
                hs[1][q2] = h2n;
                p = h2n * wlin;
            }
#pragma unroll
            for (int off = 32; off > 0; off >>= 1) p += __shfl_down(p, off);
            if (q2 == 0) { float o = p + blin; out_s = o; outp[t] = o; }
        }
        // Phase B2 (wave 0, concurrent): layer-1 update -> h1(t+1)
        if (tid < H_) {
            const float xv = xrow[t + 1];
            float gi = fmaf(wi0, xv, gall[tid]);
            float gf = fmaf(wi1, xv, gall[tid + H_]);
            float gg = fmaf(wi2, xv, gall[tid + 2 * H_]);
            float go = fmaf(wi3, xv, gall[tid + 3 * H_]);
            float ig = sigf(gi), fg = sigf(gf), gv = tanh_fast(gg), og = sigf(go);
            c1 = fmaf(fg, c1, ig * gv);
            hs[0][tid] = og * tanh_fast(c1);
        }
        __syncthreads();
    }

    // ============ future loop: t = L_-1 .. T_-1 (x <- out_s feedback) ============
    for (int t = L_ - 1; t < T_; ++t) {
        if (act) {
            const float4* h4 = (const float4*)hs[s];
            float a0 = bias, a1 = 0.f, a2 = 0.f, a3 = 0.f;
#pragma unroll
            for (int q = 0; q < NQ; ++q) {
                float4 hv = h4[q];
                a0 = fmaf(wA[q].x, hv.x, a0);
                a1 = fmaf(wA[q].y, hv.y, a1);
                a2 = fmaf(wA[q].z, hv.z, a2);
                a3 = fmaf(wA[q].w, hv.w, a3);
            }
            gdst[0] = (a0 + a1) + (a2 + a3);
        }
        __syncthreads();

        if (tid >= 256 && tid < 320) {
            float p = 0.f;
            const int q2 = tid - 256;
            if (q2 < H_) {
                float gi = gall[GP + q2]          + gall[2*GP + q2];
                float gf = gall[GP + q2 +   H_]   + gall[2*GP + q2 +   H_];
                float gg = gall[GP + q2 + 2*H_]   + gall[2*GP + q2 + 2*H_];
                float go = gall[GP + q2 + 3*H_]   + gall[2*GP + q2 + 3*H_];
                float ig = sigf(gi), fg = sigf(gf), gv = tanh_fast(gg), og = sigf(go);
                c2 = fmaf(fg, c2, ig * gv);
                float h2n = og * tanh_fast(c2);
                hs[1][q2] = h2n;
                p = h2n * wlin;
            }
#pragma unroll
            for (int off = 32; off > 0; off >>= 1) p += __shfl_down(p, off);
            if (q2 == 0) { float o = p + blin; out_s = o; outp[t] = o; }
        }
        __syncthreads();   // out_s must be visible to wave 0

        if (tid < H_) {
            const float xv = out_s;
            float gi = fmaf(wi0, xv, gall[tid]);
            float gf = fmaf(wi1, xv, gall[tid + H_]);
            float gg = fmaf(wi2, xv, gall[tid + 2 * H_]);
            float go = fmaf(wi3, xv, gall[tid + 3 * H_]);
            float ig = sigf(gi), fg = sigf(gf), gv = tanh_fast(gg), og = sigf(go);
            c1 = fmaf(fg, c1, ig * gv);
            hs[0][tid] = og * tanh_fast(c1);
        }
        __syncthreads();
    }
}

extern "C" void kernel_launch(void* const* d_in, const int* in_sizes, int n_in,
                              void* d_out, int out_size, void* d_ws, size_t ws_size,
                              hipStream_t stream)
{
    const float* x     = (const float*)d_in[0];
    const float* W_ih1 = (const float*)d_in[1];
    const float* W_hh1 = (const float*)d_in[2];
    const float* b_ih1 = (const float*)d_in[3];
    const float* b_hh1 = (const float*)d_in[4];
    const float* W_ih2 = (const float*)d_in[5];
    const float* W_hh2 = (const float*)d_in[6];
    const float* b_ih2 = (const float*)d_in[7];
    const float* b_hh2 = (const float*)d_in[8];
    const float* W_lin = (const float*)d_in[9];
    const float* b_lin = (const float*)d_in[10];
    float* out = (float*)d_out;

    lstm_pred_kernel<<<B_, 768, 0, stream>>>(x, W_ih1, W_hh1, b_ih1, b_hh1,
                                             W_ih2, W_hh2, b_ih2, b_hh2,
                                             W_lin, b_lin, out);
}